// Round 14
// baseline (51.359 us; speedup 1.0000x reference)
//
#include <hip/hip_runtime.h>
#include <math.h>

// Sizes (fixed by the problem)
#define Bb 8
#define Tt 32
#define Hh 64
#define Ww 64
#define Cc 3
#define Ff 24
#define Uu 128

typedef float v2f __attribute__((ext_vector_type(2)));

// Fast activations: |err| ~1e-6, threshold is 1.86e-4.
__device__ __forceinline__ float fast_sigmoid(float x) {
    float e = __builtin_amdgcn_exp2f(-1.442695040888963f * x);
    return __builtin_amdgcn_rcpf(1.f + e);
}
__device__ __forceinline__ float fast_tanh(float x) {
    float e = __builtin_amdgcn_exp2f(-2.885390081777927f * x);
    return 2.f * __builtin_amdgcn_rcpf(1.f + e) - 1.f;
}
// quad_perm broadcast: all 4 lanes of each quad get lane (4k+sel)'s value.
template <int CTRL>
__device__ __forceinline__ float quad_bcast(float v) {
    return __builtin_bit_cast(float,
        __builtin_amdgcn_mov_dpp(__builtin_bit_cast(int, v), CTRL, 0xF, 0xF, true));
}

// ---------------------------------------------------------------------------
// Kernel 1: fused per-frame stats + analytic double-conv + global-avg-pool
// + input-part of gate preactivations. G layout GATE-TRANSPOSED:
// G[(t*8+b)*512 + u*4 + g]. Unchanged from round 12.
// ---------------------------------------------------------------------------
__global__ void convfeat_kernel(const float* __restrict__ x,
                                const float* __restrict__ w1, const float* __restrict__ b1,
                                const float* __restrict__ w2, const float* __restrict__ b2,
                                const float* __restrict__ Wf, const float* __restrict__ bf,
                                const float* __restrict__ Wi, const float* __restrict__ bi,
                                const float* __restrict__ Wc, const float* __restrict__ bc,
                                const float* __restrict__ Wo, const float* __restrict__ bo,
                                float* __restrict__ G) {
    int n = blockIdx.x;                       // frame = b*T + t
    const float* xf = x + (size_t)n * (Hh * Ww * Cc);
    int tid  = threadIdx.x;                   // 0..255
    int row  = tid >> 2;
    int part = tid & 3;

    __shared__ float partial[256][3];
    __shared__ float rowsum[64][3];
    __shared__ float colv[64][12];
    __shared__ float st[75];                  // [c*25 + j]
    __shared__ float yst[24][9];
    __shared__ float feats[24];

    float s0 = 0.f, s1 = 0.f, s2 = 0.f;
    const float4* p4 = (const float4*)(xf + (row * Ww + part * 16) * Cc);
#pragma unroll
    for (int i = 0; i < 12; ++i) {
        float4 v = p4[i];
        int j = i * 4;
        float vv[4] = {v.x, v.y, v.z, v.w};
#pragma unroll
        for (int l = 0; l < 4; ++l) {
            int c = (j + l) % 3;
            if (c == 0) s0 += vv[l]; else if (c == 1) s1 += vv[l]; else s2 += vv[l];
        }
    }
    partial[tid][0] = s0; partial[tid][1] = s1; partial[tid][2] = s2;

    if (tid < 64) {
        int r = tid;
#pragma unroll
        for (int w4 = 0; w4 < 4; ++w4) {
            int w = (w4 < 2) ? w4 : 60 + w4;
#pragma unroll
            for (int c = 0; c < 3; ++c) colv[r][w4 * 3 + c] = xf[(r * Ww + w) * Cc + c];
        }
    }
    __syncthreads();

    if (part == 0) {
#pragma unroll
        for (int c = 0; c < 3; ++c)
            rowsum[row][c] = partial[tid][c] + partial[tid + 1][c]
                           + partial[tid + 2][c] + partial[tid + 3][c];
    }
    __syncthreads();

    if (tid < 3) {
        float t = 0.f;
        for (int r = 0; r < 64; ++r) t += rowsum[r][tid];
        st[tid * 25 + 0] = t;
    }
    if (tid >= 4 && tid < 16) {
        int k = tid - 4; int ri = k / 3, c = k % 3;
        int r = (ri < 2) ? ri : 60 + ri;
        st[c * 25 + 1 + ri] = rowsum[r][c];
    }
    if (tid >= 64 && tid < 76) {
        int k = tid - 64;
        float t = 0.f;
        for (int r = 0; r < 64; ++r) t += colv[r][k];
        int wi = k / 3, c = k % 3;
        st[c * 25 + 5 + wi] = t;
    }
    if (tid >= 128 && tid < 176) {
        int k = tid - 128; int pos = k / 3, c = k % 3;
        int ri = pos >> 2, wi = pos & 3;
        int r = (ri < 2) ? ri : 60 + ri;
        int w = (wi < 2) ? wi : 60 + wi;
        st[c * 25 + 9 + pos] = xf[(r * Ww + w) * Cc + c];
    }
    __syncthreads();

    if (tid < 24) {
        int f = tid;
        float Sy = 0, r0 = 0, r63 = 0, c0 = 0, c63 = 0, y00 = 0, y0W = 0, yH0 = 0, yHW = 0;
        for (int c = 0; c < 3; ++c) {
            const float* S = st + c * 25;
            float Sx = S[0];
            float rX[4] = {S[1], S[2], S[3], S[4]};
            float cX[4] = {S[5], S[6], S[7], S[8]};
            const float* X = S + 9;
            #define W1(p, q) w1[(((p) * 3 + (q)) * 3 + c) * 24 + f]
#pragma unroll
            for (int p = 0; p < 3; ++p)
#pragma unroll
                for (int q = 0; q < 3; ++q) {
                    float t = Sx;
                    if (p == 0) t -= rX[3];
                    if (p == 2) t -= rX[0];
                    if (q == 0) t -= cX[3];
                    if (q == 2) t -= cX[0];
                    if (p == 0 && q == 0) t += X[3 * 4 + 3];
                    if (p == 0 && q == 2) t += X[3 * 4 + 0];
                    if (p == 2 && q == 0) t += X[0 * 4 + 3];
                    if (p == 2 && q == 2) t += X[0 * 4 + 0];
                    Sy += W1(p, q) * t;
                }
#pragma unroll
            for (int q = 0; q < 3; ++q) {
                float Rr0  = rX[0] - ((q == 0) ? X[0 * 4 + 3] : 0.f) - ((q == 2) ? X[0 * 4 + 0] : 0.f);
                float Rr1  = rX[1] - ((q == 0) ? X[1 * 4 + 3] : 0.f) - ((q == 2) ? X[1 * 4 + 0] : 0.f);
                float Rr62 = rX[2] - ((q == 0) ? X[2 * 4 + 3] : 0.f) - ((q == 2) ? X[2 * 4 + 0] : 0.f);
                float Rr63 = rX[3] - ((q == 0) ? X[3 * 4 + 3] : 0.f) - ((q == 2) ? X[3 * 4 + 0] : 0.f);
                r0  += W1(1, q) * Rr0  + W1(2, q) * Rr1;
                r63 += W1(0, q) * Rr62 + W1(1, q) * Rr63;
            }
#pragma unroll
            for (int p = 0; p < 3; ++p) {
                float Rc0  = cX[0] - ((p == 0) ? X[3 * 4 + 0] : 0.f) - ((p == 2) ? X[0 * 4 + 0] : 0.f);
                float Rc1  = cX[1] - ((p == 0) ? X[3 * 4 + 1] : 0.f) - ((p == 2) ? X[0 * 4 + 1] : 0.f);
                float Rc62 = cX[2] - ((p == 0) ? X[3 * 4 + 2] : 0.f) - ((p == 2) ? X[0 * 4 + 2] : 0.f);
                float Rc63 = cX[3] - ((p == 0) ? X[3 * 4 + 3] : 0.f) - ((p == 2) ? X[0 * 4 + 3] : 0.f);
                c0  += W1(p, 1) * Rc0  + W1(p, 2) * Rc1;
                c63 += W1(p, 0) * Rc62 + W1(p, 1) * Rc63;
            }
            y00 += W1(1, 1) * X[0 * 4 + 0] + W1(1, 2) * X[0 * 4 + 1]
                 + W1(2, 1) * X[1 * 4 + 0] + W1(2, 2) * X[1 * 4 + 1];
            y0W += W1(1, 0) * X[0 * 4 + 2] + W1(1, 1) * X[0 * 4 + 3]
                 + W1(2, 0) * X[1 * 4 + 2] + W1(2, 1) * X[1 * 4 + 3];
            yH0 += W1(0, 1) * X[2 * 4 + 0] + W1(0, 2) * X[2 * 4 + 1]
                 + W1(1, 1) * X[3 * 4 + 0] + W1(1, 2) * X[3 * 4 + 1];
            yHW += W1(0, 0) * X[2 * 4 + 2] + W1(0, 1) * X[2 * 4 + 3]
                 + W1(1, 0) * X[3 * 4 + 2] + W1(1, 1) * X[3 * 4 + 3];
            #undef W1
        }
        float bb = b1[f];
        yst[f][0] = Sy + 4096.f * bb;
        yst[f][1] = r0 + 64.f * bb;
        yst[f][2] = r63 + 64.f * bb;
        yst[f][3] = c0 + 64.f * bb;
        yst[f][4] = c63 + 64.f * bb;
        yst[f][5] = y00 + bb; yst[f][6] = y0W + bb;
        yst[f][7] = yH0 + bb; yst[f][8] = yHW + bb;
    }
    __syncthreads();

    if (tid < 24) {
        int g = tid;
        float acc = 0.f;
        for (int f = 0; f < 24; ++f) {
            float Sy = yst[f][0], rY0 = yst[f][1], rY63 = yst[f][2], cY0 = yst[f][3], cY63 = yst[f][4];
            float yc00 = yst[f][5], yc0W = yst[f][6], ycH0 = yst[f][7], ycHW = yst[f][8];
#pragma unroll
            for (int p = 0; p < 3; ++p)
#pragma unroll
                for (int q = 0; q < 3; ++q) {
                    float t = Sy;
                    if (p == 0) t -= rY63;
                    if (p == 2) t -= rY0;
                    if (q == 0) t -= cY63;
                    if (q == 2) t -= cY0;
                    if (p == 0 && q == 0) t += ycHW;
                    if (p == 0 && q == 2) t += ycH0;
                    if (p == 2 && q == 0) t += yc0W;
                    if (p == 2 && q == 2) t += yc00;
                    acc += w2[(((p * 3 + q) * 24 + f) * 24) + g] * t;
                }
        }
        feats[g] = b2[g] + acc * (1.f / 4096.f);
    }
    __syncthreads();

    int b = n >> 5, t = n & 31;               // Tt = 32
    float* Gdst = G + ((size_t)(t * Bb + b)) * 512;
#pragma unroll
    for (int rep = 0; rep < 2; ++rep) {
        int col = tid + rep * 256;
        int gg = col >> 7, u = col & 127;
        const float* W    = (gg == 0) ? Wf : (gg == 1) ? Wi : (gg == 2) ? Wc : Wo;
        const float* bias = (gg == 0) ? bf : (gg == 1) ? bi : (gg == 2) ? bc : bo;
        float acc = bias[u];
#pragma unroll
        for (int k = 0; k < Ff; ++k) acc += feats[k] * W[k * Uu + u];
        Gdst[u * 4 + gg] = acc;               // [u][gate] layout
    }
}

// ---------------------------------------------------------------------------
// Kernel 2: LSTM — NO partial exchange. 512 threads, 8 waves, one batch.
// Thread tid owns the FULL K=128 column of (unit u = tid>>2, gate g = tid&3):
// 64 named v2f weights (k-pairs), 32 broadcast ds_read_b128 for h, 64
// elementwise pk_fma. A unit's 4 gates live in ADJACENT LANES of a quad, so
// the gate gather is 4 v_mov_dpp quad_perm ops (pure VALU — no LDS, no
// second barrier). All 4 lanes of a quad redundantly compute the identical
// c/h update; g==0 lanes write h (parity double-buffered) -> ONE barrier.
// This removes the part[] LDS round-trip (~200 cyc) + redundant phase-B
// reads that r11's accounting identified as the per-step cost floor.
// r13 (hand-asm, spill-impossible) proved weights-residency is NOT the
// issue; cutting per-step cycles is.
// ---------------------------------------------------------------------------
__global__ __launch_bounds__(512)
__attribute__((amdgpu_waves_per_eu(2, 2)))
void lstm_kernel(
        const float* __restrict__ G,
        const float* __restrict__ Wf, const float* __restrict__ Wi,
        const float* __restrict__ Wc, const float* __restrict__ Wo,
        const float* __restrict__ out_w, const float* __restrict__ out_b,
        float* __restrict__ out) {
    int b   = blockIdx.x;
    int tid = threadIdx.x;
    int u   = tid >> 2;                       // unit 0..127
    int g   = tid & 3;                        // gate
    const float* Wg = (g == 0) ? Wf : (g == 1) ? Wi : (g == 2) ? Wc : Wo;

    // 128 weight VGPRs: 64 named v2f, pair i = rows (24+2i, 24+2i+1), col u.
    const float* wb = Wg + (size_t)Ff * Uu + u;
#define LDW(i) v2f w##i = { wb[(size_t)(2*(i)) * Uu], wb[(size_t)(2*(i)+1) * Uu] }
    LDW(0);  LDW(1);  LDW(2);  LDW(3);  LDW(4);  LDW(5);  LDW(6);  LDW(7);
    LDW(8);  LDW(9);  LDW(10); LDW(11); LDW(12); LDW(13); LDW(14); LDW(15);
    LDW(16); LDW(17); LDW(18); LDW(19); LDW(20); LDW(21); LDW(22); LDW(23);
    LDW(24); LDW(25); LDW(26); LDW(27); LDW(28); LDW(29); LDW(30); LDW(31);
    LDW(32); LDW(33); LDW(34); LDW(35); LDW(36); LDW(37); LDW(38); LDW(39);
    LDW(40); LDW(41); LDW(42); LDW(43); LDW(44); LDW(45); LDW(46); LDW(47);
    LDW(48); LDW(49); LDW(50); LDW(51); LDW(52); LDW(53); LDW(54); LDW(55);
    LDW(56); LDW(57); LDW(58); LDW(59); LDW(60); LDW(61); LDW(62); LDW(63);
#undef LDW
#define KA8(p0,p1,p2,p3,p4,p5,p6,p7) asm volatile("" : "+v"(p0),"+v"(p1),\
        "+v"(p2),"+v"(p3),"+v"(p4),"+v"(p5),"+v"(p6),"+v"(p7))
    KA8(w0,w1,w2,w3,w4,w5,w6,w7);         KA8(w8,w9,w10,w11,w12,w13,w14,w15);
    KA8(w16,w17,w18,w19,w20,w21,w22,w23); KA8(w24,w25,w26,w27,w28,w29,w30,w31);
    KA8(w32,w33,w34,w35,w36,w37,w38,w39); KA8(w40,w41,w42,w43,w44,w45,w46,w47);
    KA8(w48,w49,w50,w51,w52,w53,w54,w55); KA8(w56,w57,w58,w59,w60,w61,w62,w63);
#undef KA8

    __shared__ __align__(16) float Gl[Tt][512];   // 64 KB, [t][u*4+g]
    __shared__ __align__(16) float hsb[2][Uu];    // h double buffer
    __shared__ __align__(16) float hist[Tt][Uu];  // 16 KB

    // Prologue: copy G[b] slab (32x512) to LDS, coalesced.
    {
        int r  = tid >> 4;
        int cc = (tid & 15) * 32;
        const float4* src = (const float4*)(G + ((size_t)(r * Bb + b)) * 512 + cc);
        float4* dst = (float4*)(&Gl[r][cc]);
#pragma unroll
        for (int i = 0; i < 8; ++i) dst[i] = src[i];
    }
    if (tid < Uu) hsb[0][tid] = 0.f;
    float cs = 0.f;
    __syncthreads();

#pragma clang loop unroll(disable)
    for (int t = 0; t < Tt; ++t) {
        float gx = Gl[t][tid];                // per-lane b32, conflict-free
        const float4* hp = (const float4*)hsb[t & 1];   // broadcast reads
        v2f a0 = {0.f, 0.f}, a1 = {0.f, 0.f};
#define ST4(j) { float4 h4 = hp[j]; \
        v2f hlo = {h4.x, h4.y}, hhi = {h4.z, h4.w}; \
        asm("v_pk_fma_f32 %0, %1, %2, %0" : "+v"(a0) : "v"(w##j##_E), "v"(hlo)); \
        asm("v_pk_fma_f32 %0, %1, %2, %0" : "+v"(a1) : "v"(w##j##_O), "v"(hhi)); }
        // (macro needs token pasting per index; expand manually)
#undef ST4
#define STQ(j, wE, wO) { float4 h4 = hp[j]; \
        v2f hlo = {h4.x, h4.y}, hhi = {h4.z, h4.w}; \
        asm("v_pk_fma_f32 %0, %1, %2, %0" : "+v"(a0) : "v"(wE), "v"(hlo)); \
        asm("v_pk_fma_f32 %0, %1, %2, %0" : "+v"(a1) : "v"(wO), "v"(hhi)); }
        STQ(0,  w0,  w1);   STQ(1,  w2,  w3);   STQ(2,  w4,  w5);
        STQ(3,  w6,  w7);   STQ(4,  w8,  w9);   STQ(5,  w10, w11);
        STQ(6,  w12, w13);  STQ(7,  w14, w15);  STQ(8,  w16, w17);
        STQ(9,  w18, w19);  STQ(10, w20, w21);  STQ(11, w22, w23);
        STQ(12, w24, w25);  STQ(13, w26, w27);  STQ(14, w28, w29);
        STQ(15, w30, w31);  STQ(16, w32, w33);  STQ(17, w34, w35);
        STQ(18, w36, w37);  STQ(19, w38, w39);  STQ(20, w40, w41);
        STQ(21, w42, w43);  STQ(22, w44, w45);  STQ(23, w46, w47);
        STQ(24, w48, w49);  STQ(25, w50, w51);  STQ(26, w52, w53);
        STQ(27, w54, w55);  STQ(28, w56, w57);  STQ(29, w58, w59);
        STQ(30, w60, w61);  STQ(31, w62, w63);
#undef STQ
        float z = (a0.x + a0.y) + (a1.x + a1.y) + gx;

        // gather the quad's 4 gate values (pure VALU, no LDS):
        float zf = quad_bcast<0x00>(z);       // lane 4k+0 -> all
        float zi = quad_bcast<0x55>(z);       // lane 4k+1 -> all
        float zg = quad_bcast<0xAA>(z);       // lane 4k+2 -> all
        float zo = quad_bcast<0xFF>(z);       // lane 4k+3 -> all

        float ff = fast_sigmoid(zf);
        float ii = fast_sigmoid(zi);
        float gg = fast_tanh(zg);
        float oo = fast_sigmoid(zo);
        cs = cs * ff + ii * gg;               // identical across the quad
        float hn = fast_tanh(cs) * oo;
        if (g == 0) {
            hsb[(t + 1) & 1][u] = hn;
            hist[t][u] = hn;
        }
        __syncthreads();                      // the ONLY barrier per step
    }

    // Epilogue: out[b][t] = hist[t] . out_w + out_b, 16 threads per t.
    int tt = tid >> 4, j = tid & 15;
    const float4* hh = (const float4*)(&hist[tt][j * 8]);
    float4 a0q = hh[0], a1q = hh[1];
    const float* owp = out_w + j * 8;
    float pwv = a0q.x * owp[0] + a0q.y * owp[1] + a0q.z * owp[2] + a0q.w * owp[3]
              + a1q.x * owp[4] + a1q.y * owp[5] + a1q.z * owp[6] + a1q.w * owp[7];
#pragma unroll
    for (int off = 8; off > 0; off >>= 1) pwv += __shfl_down(pwv, off, 16);
    if (j == 0) out[b * Tt + tt] = pwv + out_b[0];
}

// ---------------------------------------------------------------------------
extern "C" void kernel_launch(void* const* d_in, const int* in_sizes, int n_in,
                              void* d_out, int out_size, void* d_ws, size_t ws_size,
                              hipStream_t stream) {
    const float* x   = (const float*)d_in[0];
    const float* w1  = (const float*)d_in[1];
    const float* b1  = (const float*)d_in[2];
    const float* w2  = (const float*)d_in[3];
    const float* b2  = (const float*)d_in[4];
    const float* Wf  = (const float*)d_in[5];
    const float* bf  = (const float*)d_in[6];
    const float* Wi  = (const float*)d_in[7];
    const float* bi  = (const float*)d_in[8];
    const float* Wc  = (const float*)d_in[9];
    const float* bc  = (const float*)d_in[10];
    const float* Wo  = (const float*)d_in[11];
    const float* bo  = (const float*)d_in[12];
    const float* ow  = (const float*)d_in[13];
    const float* ob  = (const float*)d_in[14];
    float* out = (float*)d_out;

    float* G = (float*)d_ws;                  // 256*512 = 131072 floats

    convfeat_kernel<<<Bb * Tt, 256, 0, stream>>>(x, w1, b1, w2, b2,
                                                 Wf, bf, Wi, bi, Wc, bc, Wo, bo, G);
    lstm_kernel<<<Bb, 512, 0, stream>>>(G, Wf, Wi, Wc, Wo, ow, ob, out);
}

// Round 15
// 40.402 us; speedup vs baseline: 1.2712x; 1.2712x over previous
//
#include <hip/hip_runtime.h>
#include <math.h>

// Sizes (fixed by the problem)
#define Bb 8
#define Tt 32
#define Hh 64
#define Ww 64
#define Cc 3
#define Ff 24
#define Uu 128

// ---------------------------------------------------------------------------
// Kernel 1: fused per-frame stats + analytic double-conv + global-avg-pool
// + input-part of gate preactivations. G layout GATE-TRANSPOSED:
// G[(t*8+b)*512 + u*4 + g]. Unchanged (verified r12/r13).
// ---------------------------------------------------------------------------
__global__ void convfeat_kernel(const float* __restrict__ x,
                                const float* __restrict__ w1, const float* __restrict__ b1,
                                const float* __restrict__ w2, const float* __restrict__ b2,
                                const float* __restrict__ Wf, const float* __restrict__ bf,
                                const float* __restrict__ Wi, const float* __restrict__ bi,
                                const float* __restrict__ Wc, const float* __restrict__ bc,
                                const float* __restrict__ Wo, const float* __restrict__ bo,
                                float* __restrict__ G) {
    int n = blockIdx.x;                       // frame = b*T + t
    const float* xf = x + (size_t)n * (Hh * Ww * Cc);
    int tid  = threadIdx.x;                   // 0..255
    int row  = tid >> 2;
    int part = tid & 3;

    __shared__ float partial[256][3];
    __shared__ float rowsum[64][3];
    __shared__ float colv[64][12];
    __shared__ float st[75];                  // [c*25 + j]
    __shared__ float yst[24][9];
    __shared__ float feats[24];

    float s0 = 0.f, s1 = 0.f, s2 = 0.f;
    const float4* p4 = (const float4*)(xf + (row * Ww + part * 16) * Cc);
#pragma unroll
    for (int i = 0; i < 12; ++i) {
        float4 v = p4[i];
        int j = i * 4;
        float vv[4] = {v.x, v.y, v.z, v.w};
#pragma unroll
        for (int l = 0; l < 4; ++l) {
            int c = (j + l) % 3;
            if (c == 0) s0 += vv[l]; else if (c == 1) s1 += vv[l]; else s2 += vv[l];
        }
    }
    partial[tid][0] = s0; partial[tid][1] = s1; partial[tid][2] = s2;

    if (tid < 64) {
        int r = tid;
#pragma unroll
        for (int w4 = 0; w4 < 4; ++w4) {
            int w = (w4 < 2) ? w4 : 60 + w4;
#pragma unroll
            for (int c = 0; c < 3; ++c) colv[r][w4 * 3 + c] = xf[(r * Ww + w) * Cc + c];
        }
    }
    __syncthreads();

    if (part == 0) {
#pragma unroll
        for (int c = 0; c < 3; ++c)
            rowsum[row][c] = partial[tid][c] + partial[tid + 1][c]
                           + partial[tid + 2][c] + partial[tid + 3][c];
    }
    __syncthreads();

    if (tid < 3) {
        float t = 0.f;
        for (int r = 0; r < 64; ++r) t += rowsum[r][tid];
        st[tid * 25 + 0] = t;
    }
    if (tid >= 4 && tid < 16) {
        int k = tid - 4; int ri = k / 3, c = k % 3;
        int r = (ri < 2) ? ri : 60 + ri;
        st[c * 25 + 1 + ri] = rowsum[r][c];
    }
    if (tid >= 64 && tid < 76) {
        int k = tid - 64;
        float t = 0.f;
        for (int r = 0; r < 64; ++r) t += colv[r][k];
        int wi = k / 3, c = k % 3;
        st[c * 25 + 5 + wi] = t;
    }
    if (tid >= 128 && tid < 176) {
        int k = tid - 128; int pos = k / 3, c = k % 3;
        int ri = pos >> 2, wi = pos & 3;
        int r = (ri < 2) ? ri : 60 + ri;
        int w = (wi < 2) ? wi : 60 + wi;
        st[c * 25 + 9 + pos] = xf[(r * Ww + w) * Cc + c];
    }
    __syncthreads();

    if (tid < 24) {
        int f = tid;
        float Sy = 0, r0 = 0, r63 = 0, c0 = 0, c63 = 0, y00 = 0, y0W = 0, yH0 = 0, yHW = 0;
        for (int c = 0; c < 3; ++c) {
            const float* S = st + c * 25;
            float Sx = S[0];
            float rX[4] = {S[1], S[2], S[3], S[4]};
            float cX[4] = {S[5], S[6], S[7], S[8]};
            const float* X = S + 9;
            #define W1(p, q) w1[(((p) * 3 + (q)) * 3 + c) * 24 + f]
#pragma unroll
            for (int p = 0; p < 3; ++p)
#pragma unroll
                for (int q = 0; q < 3; ++q) {
                    float t = Sx;
                    if (p == 0) t -= rX[3];
                    if (p == 2) t -= rX[0];
                    if (q == 0) t -= cX[3];
                    if (q == 2) t -= cX[0];
                    if (p == 0 && q == 0) t += X[3 * 4 + 3];
                    if (p == 0 && q == 2) t += X[3 * 4 + 0];
                    if (p == 2 && q == 0) t += X[0 * 4 + 3];
                    if (p == 2 && q == 2) t += X[0 * 4 + 0];
                    Sy += W1(p, q) * t;
                }
#pragma unroll
            for (int q = 0; q < 3; ++q) {
                float Rr0  = rX[0] - ((q == 0) ? X[0 * 4 + 3] : 0.f) - ((q == 2) ? X[0 * 4 + 0] : 0.f);
                float Rr1  = rX[1] - ((q == 0) ? X[1 * 4 + 3] : 0.f) - ((q == 2) ? X[1 * 4 + 0] : 0.f);
                float Rr62 = rX[2] - ((q == 0) ? X[2 * 4 + 3] : 0.f) - ((q == 2) ? X[2 * 4 + 0] : 0.f);
                float Rr63 = rX[3] - ((q == 0) ? X[3 * 4 + 3] : 0.f) - ((q == 2) ? X[3 * 4 + 0] : 0.f);
                r0  += W1(1, q) * Rr0  + W1(2, q) * Rr1;
                r63 += W1(0, q) * Rr62 + W1(1, q) * Rr63;
            }
#pragma unroll
            for (int p = 0; p < 3; ++p) {
                float Rc0  = cX[0] - ((p == 0) ? X[3 * 4 + 0] : 0.f) - ((p == 2) ? X[0 * 4 + 0] : 0.f);
                float Rc1  = cX[1] - ((p == 0) ? X[3 * 4 + 1] : 0.f) - ((p == 2) ? X[0 * 4 + 1] : 0.f);
                float Rc62 = cX[2] - ((p == 0) ? X[3 * 4 + 2] : 0.f) - ((p == 2) ? X[0 * 4 + 2] : 0.f);
                float Rc63 = cX[3] - ((p == 0) ? X[3 * 4 + 3] : 0.f) - ((p == 2) ? X[0 * 4 + 3] : 0.f);
                c0  += W1(p, 1) * Rc0  + W1(p, 2) * Rc1;
                c63 += W1(p, 0) * Rc62 + W1(p, 1) * Rc63;
            }
            y00 += W1(1, 1) * X[0 * 4 + 0] + W1(1, 2) * X[0 * 4 + 1]
                 + W1(2, 1) * X[1 * 4 + 0] + W1(2, 2) * X[1 * 4 + 1];
            y0W += W1(1, 0) * X[0 * 4 + 2] + W1(1, 1) * X[0 * 4 + 3]
                 + W1(2, 0) * X[1 * 4 + 2] + W1(2, 1) * X[1 * 4 + 3];
            yH0 += W1(0, 1) * X[2 * 4 + 0] + W1(0, 2) * X[2 * 4 + 1]
                 + W1(1, 1) * X[3 * 4 + 0] + W1(1, 2) * X[3 * 4 + 1];
            yHW += W1(0, 0) * X[2 * 4 + 2] + W1(0, 1) * X[2 * 4 + 3]
                 + W1(1, 0) * X[3 * 4 + 2] + W1(1, 1) * X[3 * 4 + 3];
            #undef W1
        }
        float bb = b1[f];
        yst[f][0] = Sy + 4096.f * bb;
        yst[f][1] = r0 + 64.f * bb;
        yst[f][2] = r63 + 64.f * bb;
        yst[f][3] = c0 + 64.f * bb;
        yst[f][4] = c63 + 64.f * bb;
        yst[f][5] = y00 + bb; yst[f][6] = y0W + bb;
        yst[f][7] = yH0 + bb; yst[f][8] = yHW + bb;
    }
    __syncthreads();

    if (tid < 24) {
        int g = tid;
        float acc = 0.f;
        for (int f = 0; f < 24; ++f) {
            float Sy = yst[f][0], rY0 = yst[f][1], rY63 = yst[f][2], cY0 = yst[f][3], cY63 = yst[f][4];
            float yc00 = yst[f][5], yc0W = yst[f][6], ycH0 = yst[f][7], ycHW = yst[f][8];
#pragma unroll
            for (int p = 0; p < 3; ++p)
#pragma unroll
                for (int q = 0; q < 3; ++q) {
                    float t = Sy;
                    if (p == 0) t -= rY63;
                    if (p == 2) t -= rY0;
                    if (q == 0) t -= cY63;
                    if (q == 2) t -= cY0;
                    if (p == 0 && q == 0) t += ycHW;
                    if (p == 0 && q == 2) t += ycH0;
                    if (p == 2 && q == 0) t += yc0W;
                    if (p == 2 && q == 2) t += yc00;
                    acc += w2[(((p * 3 + q) * 24 + f) * 24) + g] * t;
                }
        }
        feats[g] = b2[g] + acc * (1.f / 4096.f);
    }
    __syncthreads();

    int b = n >> 5, t = n & 31;               // Tt = 32
    float* Gdst = G + ((size_t)(t * Bb + b)) * 512;
#pragma unroll
    for (int rep = 0; rep < 2; ++rep) {
        int col = tid + rep * 256;
        int gg = col >> 7, u = col & 127;
        const float* W    = (gg == 0) ? Wf : (gg == 1) ? Wi : (gg == 2) ? Wc : Wo;
        const float* bias = (gg == 0) ? bf : (gg == 1) ? bi : (gg == 2) ? bc : bo;
        float acc = bias[u];
#pragma unroll
        for (int k = 0; k < Ff; ++k) acc += feats[k] * W[k * Uu + u];
        Gdst[u * 4 + gg] = acc;               // [u][gate] layout
    }
}

// ===========================================================================
// Kernel 2: LSTM — hand-allocated asm (r13 skeleton, VERIFIED correct +
// spill-proof) with phase A rebuilt: 8 broadcast ds_read_b128 + 64
// v_pk_fma_f32 on row-pair weight registers (replaces 32 readlane + 128
// scalar fmac -> ~half the per-step instructions). h lives in a tiny
// parity-double-buffered LDS array written by the SAME wave that reads it
// (one barrier/step). G's b128 is prefetched during phase A.
// Register map: v64..95=Wf rows0..31 | v96..127=Wi | v128..159=Wc |
// v160..191=Wo (pairs (2i,2i+1) are pk operands); v33=cs, v34..41=pk accs,
// v44..63 temps/reads, v24..29 = addresses (pw,pr,gA,hist,hread,hwrite).
// ===========================================================================
#define LD8(d0,d1,d2,d3,d4,d5,d6,d7) \
  "global_load_dword v" #d0 ", v[46:47], off\n\t" \
  "global_load_dword v" #d1 ", v[46:47], off offset:512\n\t" \
  "global_load_dword v" #d2 ", v[46:47], off offset:1024\n\t" \
  "global_load_dword v" #d3 ", v[46:47], off offset:1536\n\t" \
  "global_load_dword v" #d4 ", v[46:47], off offset:2048\n\t" \
  "global_load_dword v" #d5 ", v[46:47], off offset:2560\n\t" \
  "global_load_dword v" #d6 ", v[46:47], off offset:3072\n\t" \
  "global_load_dword v" #d7 ", v[46:47], off offset:3584\n\t"
#define BUMP \
  "v_add_co_u32 v46, vcc, 0x1000, v46\n\t" \
  "v_addc_co_u32 v47, vcc, 0, v47, vcc\n\t"
// 4 gates x one h-pair: acc_g += W_g[rowpair] * (h_lo, h_hi)
#define PKQ(f0,f1,i0,i1,c0,c1,o0,o1,h0,h1) \
  "v_pk_fma_f32 v[34:35], v[" #f0 ":" #f1 "], v[" #h0 ":" #h1 "], v[34:35]\n\t" \
  "v_pk_fma_f32 v[36:37], v[" #i0 ":" #i1 "], v[" #h0 ":" #h1 "], v[36:37]\n\t" \
  "v_pk_fma_f32 v[38:39], v[" #c0 ":" #c1 "], v[" #h0 ":" #h1 "], v[38:39]\n\t" \
  "v_pk_fma_f32 v[40:41], v[" #o0 ":" #o1 "], v[" #h0 ":" #h1 "], v[40:41]\n\t"

__global__ __launch_bounds__(512) void lstm_kernel(
        const float* __restrict__ G,
        const float* __restrict__ Wf, const float* __restrict__ Wi,
        const float* __restrict__ Wc, const float* __restrict__ Wo,
        const float* __restrict__ out_w, const float* __restrict__ out_b,
        float* __restrict__ out) {
    int b   = blockIdx.x;
    int tid = threadIdx.x;
    int w   = tid >> 6;                       // wave 0..7
    int l   = tid & 63;
    int q   = w >> 1;                         // row chunk (rows 32q..+32)
    int uc  = ((w & 1) << 6) | l;             // phase-A unit-column
    int u   = (q << 5) | (l & 31);            // phase-B unit (own wave's chunk)

    __shared__ __align__(16)    float Gl[Tt][Uu * 4];   // 64 KB, [t][u*4+g]
    __shared__ __align__(16384) float prt[2][4][Uu][4]; // 16 KB, parity-dbuf
    __shared__ __align__(16)    float hist[Tt][Uu];     // 16 KB
    __shared__ __align__(1024)  float hsb[2][Uu];       // 1 KB, h parity-dbuf

    // Prologue: copy G[b] slab (32x512) to LDS, coalesced; zero h buffer 0.
    {
        int r  = tid >> 4;
        int cc = (tid & 15) * 32;
        const float4* src = (const float4*)(G + ((size_t)(r * Bb + b)) * 512 + cc);
        float4* dst = (float4*)(&Gl[r][cc]);
#pragma unroll
        for (int i = 0; i < 8; ++i) dst[i] = src[i];
    }
    if (tid < Uu) hsb[0][tid] = 0.f;
    __syncthreads();

    const float* Wfp = Wf + (size_t)(Ff + 32 * q) * Uu + uc;
    const float* Wip = Wi + (size_t)(Ff + 32 * q) * Uu + uc;
    const float* Wcp = Wc + (size_t)(Ff + 32 * q) * Uu + uc;
    const float* Wop = Wo + (size_t)(Ff + 32 * q) * Uu + uc;
    unsigned f_lo = (unsigned)(uintptr_t)Wfp, f_hi = (unsigned)((uintptr_t)Wfp >> 32);
    unsigned i_lo = (unsigned)(uintptr_t)Wip, i_hi = (unsigned)((uintptr_t)Wip >> 32);
    unsigned c_lo = (unsigned)(uintptr_t)Wcp, c_hi = (unsigned)((uintptr_t)Wcp >> 32);
    unsigned o_lo = (unsigned)(uintptr_t)Wop, o_hi = (unsigned)((uintptr_t)Wop >> 32);
    unsigned pw  = (unsigned)(uintptr_t)&prt[0][q][uc][0];  // part write
    unsigned pr  = (unsigned)(uintptr_t)&prt[0][0][u][0];   // part read base
    unsigned ga  = (unsigned)(uintptr_t)&Gl[0][u * 4];      // G read
    unsigned ha  = (unsigned)(uintptr_t)&hist[0][u];        // hist write
    unsigned hra = (unsigned)(uintptr_t)&hsb[0][q * 32];    // h read (parity 0)
    unsigned hwa = (unsigned)(uintptr_t)&hsb[1][u];         // h write (parity 1)

    asm volatile(
        // ---------- weight loads into fixed v64..v191 (rows sequential) ---
        "v_mov_b32 v46, %0\n\t" "v_mov_b32 v47, %1\n\t"
        LD8(64,65,66,67,68,69,70,71) BUMP
        LD8(72,73,74,75,76,77,78,79) BUMP
        LD8(80,81,82,83,84,85,86,87) BUMP
        LD8(88,89,90,91,92,93,94,95)
        "v_mov_b32 v46, %2\n\t" "v_mov_b32 v47, %3\n\t"
        LD8(96,97,98,99,100,101,102,103) BUMP
        LD8(104,105,106,107,108,109,110,111) BUMP
        LD8(112,113,114,115,116,117,118,119) BUMP
        LD8(120,121,122,123,124,125,126,127)
        "v_mov_b32 v46, %4\n\t" "v_mov_b32 v47, %5\n\t"
        LD8(128,129,130,131,132,133,134,135) BUMP
        LD8(136,137,138,139,140,141,142,143) BUMP
        LD8(144,145,146,147,148,149,150,151) BUMP
        LD8(152,153,154,155,156,157,158,159)
        "v_mov_b32 v46, %6\n\t" "v_mov_b32 v47, %7\n\t"
        LD8(160,161,162,163,164,165,166,167) BUMP
        LD8(168,169,170,171,172,173,174,175) BUMP
        LD8(176,177,178,179,180,181,182,183) BUMP
        LD8(184,185,186,187,188,189,190,191)
        "s_waitcnt vmcnt(0)\n\t"
        // ---------- loop state ----------
        "v_mov_b32 v24, %8\n\t"               // part write addr
        "v_mov_b32 v25, %9\n\t"               // part read base
        "v_mov_b32 v26, %10\n\t"              // G addr
        "v_mov_b32 v27, %11\n\t"              // hist addr
        "v_mov_b32 v28, %12\n\t"              // h read addr
        "v_mov_b32 v29, %13\n\t"              // h write addr
        "v_mov_b32 v33, 0\n\t"                // cs
        "s_mov_b32 s22, 32\n\t"
        "Lstep_%=:\n\t"
        // ---------- phase A: h batch 1 (16 h) ----------
        "ds_read_b128 v[44:47], v28\n\t"
        "ds_read_b128 v[48:51], v28 offset:16\n\t"
        "ds_read_b128 v[52:55], v28 offset:32\n\t"
        "ds_read_b128 v[56:59], v28 offset:48\n\t"
        "v_mov_b32 v34, 0\n\t" "v_mov_b32 v35, 0\n\t"
        "v_mov_b32 v36, 0\n\t" "v_mov_b32 v37, 0\n\t"
        "v_mov_b32 v38, 0\n\t" "v_mov_b32 v39, 0\n\t"
        "v_mov_b32 v40, 0\n\t" "v_mov_b32 v41, 0\n\t"
        "s_waitcnt lgkmcnt(0)\n\t"
        PKQ(64,65, 96,97, 128,129, 160,161, 44,45)
        PKQ(66,67, 98,99, 130,131, 162,163, 46,47)
        PKQ(68,69, 100,101, 132,133, 164,165, 48,49)
        PKQ(70,71, 102,103, 134,135, 166,167, 50,51)
        PKQ(72,73, 104,105, 136,137, 168,169, 52,53)
        PKQ(74,75, 106,107, 138,139, 170,171, 54,55)
        PKQ(76,77, 108,109, 140,141, 172,173, 56,57)
        PKQ(78,79, 110,111, 142,143, 174,175, 58,59)
        // ---------- phase A: h batch 2 (16 h) + G prefetch ----------
        "ds_read_b128 v[44:47], v28 offset:64\n\t"
        "ds_read_b128 v[48:51], v28 offset:80\n\t"
        "ds_read_b128 v[52:55], v28 offset:96\n\t"
        "ds_read_b128 v[56:59], v28 offset:112\n\t"
        "ds_read_b128 v[60:63], v26\n\t"
        "s_waitcnt lgkmcnt(1)\n\t"
        PKQ(80,81, 112,113, 144,145, 176,177, 44,45)
        PKQ(82,83, 114,115, 146,147, 178,179, 46,47)
        PKQ(84,85, 116,117, 148,149, 180,181, 48,49)
        PKQ(86,87, 118,119, 150,151, 182,183, 50,51)
        PKQ(88,89, 120,121, 152,153, 184,185, 52,53)
        PKQ(90,91, 122,123, 154,155, 186,187, 54,55)
        PKQ(92,93, 124,125, 156,157, 188,189, 56,57)
        PKQ(94,95, 126,127, 158,159, 190,191, 58,59)
        // collapse pk pairs -> z_f,z_i,z_c,z_o in v34..v37
        "v_add_f32 v34, v34, v35\n\t"
        "v_add_f32 v35, v36, v37\n\t"
        "v_add_f32 v36, v38, v39\n\t"
        "v_add_f32 v37, v40, v41\n\t"
        "ds_write_b128 v24, v[34:37]\n\t"
        "s_waitcnt lgkmcnt(0)\n\t"
        "s_barrier\n\t"
        // ---------- phase B: 4 part reads (G already in v60..63) ----------
        "ds_read_b128 v[44:47], v25\n\t"
        "ds_read_b128 v[48:51], v25 offset:2048\n\t"
        "ds_read_b128 v[52:55], v25 offset:4096\n\t"
        "ds_read_b128 v[56:59], v25 offset:6144\n\t"
        "s_waitcnt lgkmcnt(0)\n\t"
        "v_add_f32 v44, v44, v48\n\t" "v_add_f32 v45, v45, v49\n\t"
        "v_add_f32 v46, v46, v50\n\t" "v_add_f32 v47, v47, v51\n\t"
        "v_add_f32 v52, v52, v56\n\t" "v_add_f32 v53, v53, v57\n\t"
        "v_add_f32 v54, v54, v58\n\t" "v_add_f32 v55, v55, v59\n\t"
        "v_add_f32 v44, v44, v52\n\t" "v_add_f32 v45, v45, v53\n\t"
        "v_add_f32 v46, v46, v54\n\t" "v_add_f32 v47, v47, v55\n\t"
        "v_add_f32 v44, v44, v60\n\t" "v_add_f32 v45, v45, v61\n\t"
        "v_add_f32 v46, v46, v62\n\t" "v_add_f32 v47, v47, v63\n\t"
        // activations (verified r13): sigmoid via exp2(-1.4427x); tanh via 2*sig(2x)-1
        "v_mul_f32 v48, 0xbfb8aa3b, v44\n\t"
        "v_mul_f32 v49, 0xbfb8aa3b, v45\n\t"
        "v_mul_f32 v50, 0xc038aa3b, v46\n\t"
        "v_mul_f32 v51, 0xbfb8aa3b, v47\n\t"
        "v_exp_f32 v48, v48\n\t" "v_exp_f32 v49, v49\n\t"
        "v_exp_f32 v50, v50\n\t" "v_exp_f32 v51, v51\n\t"
        "s_nop 1\n\t"
        "v_add_f32 v48, 1.0, v48\n\t" "v_add_f32 v49, 1.0, v49\n\t"
        "v_add_f32 v50, 1.0, v50\n\t" "v_add_f32 v51, 1.0, v51\n\t"
        "v_rcp_f32 v48, v48\n\t" "v_rcp_f32 v49, v49\n\t"
        "v_rcp_f32 v50, v50\n\t" "v_rcp_f32 v51, v51\n\t"
        "s_nop 1\n\t"
        "v_mul_f32 v50, 2.0, v50\n\t"
        "v_add_f32 v50, -1.0, v50\n\t"
        "v_mul_f32 v33, v33, v48\n\t"         // cs *= f
        "v_fmac_f32 v33, v49, v50\n\t"        // cs += i*g
        "v_mul_f32 v52, 0xc038aa3b, v33\n\t"
        "v_exp_f32 v52, v52\n\t"
        "s_nop 1\n\t"
        "v_add_f32 v52, 1.0, v52\n\t"
        "v_rcp_f32 v52, v52\n\t"
        "s_nop 1\n\t"
        "v_mul_f32 v52, 2.0, v52\n\t"
        "v_add_f32 v52, -1.0, v52\n\t"        // tanh(cs)
        "v_mul_f32 v32, v52, v51\n\t"         // hn = tanh(cs)*o
        "ds_write_b32 v29, v32\n\t"           // hsb[(t+1)&1][u]
        "ds_write_b32 v27, v32\n\t"           // hist[t][u]
        // address bumps + loop
        "v_add_u32 v26, 0x800, v26\n\t"
        "v_add_u32 v27, 0x200, v27\n\t"
        "v_xor_b32 v24, 0x2000, v24\n\t"
        "v_xor_b32 v25, 0x2000, v25\n\t"
        "v_xor_b32 v28, 0x200, v28\n\t"
        "v_xor_b32 v29, 0x200, v29\n\t"
        "s_sub_u32 s22, s22, 1\n\t"
        "s_cmp_lg_u32 s22, 0\n\t"
        "s_cbranch_scc1 Lstep_%=\n\t"
        "s_waitcnt lgkmcnt(0)\n\t"
        :
        : "v"(f_lo), "v"(f_hi), "v"(i_lo), "v"(i_hi),
          "v"(c_lo), "v"(c_hi), "v"(o_lo), "v"(o_hi),
          "v"(pw), "v"(pr), "v"(ga), "v"(ha), "v"(hra), "v"(hwa)
        : "memory", "vcc", "scc", "s22",
          "v24","v25","v26","v27","v28","v29","v30","v31",
          "v32","v33","v34","v35","v36","v37","v38","v39",
          "v40","v41","v42","v43","v44","v45","v46","v47",
          "v48","v49","v50","v51","v52","v53","v54","v55",
          "v56","v57","v58","v59","v60","v61","v62","v63",
          "v64","v65","v66","v67","v68","v69","v70","v71",
          "v72","v73","v74","v75","v76","v77","v78","v79",
          "v80","v81","v82","v83","v84","v85","v86","v87",
          "v88","v89","v90","v91","v92","v93","v94","v95",
          "v96","v97","v98","v99","v100","v101","v102","v103",
          "v104","v105","v106","v107","v108","v109","v110","v111",
          "v112","v113","v114","v115","v116","v117","v118","v119",
          "v120","v121","v122","v123","v124","v125","v126","v127",
          "v128","v129","v130","v131","v132","v133","v134","v135",
          "v136","v137","v138","v139","v140","v141","v142","v143",
          "v144","v145","v146","v147","v148","v149","v150","v151",
          "v152","v153","v154","v155","v156","v157","v158","v159",
          "v160","v161","v162","v163","v164","v165","v166","v167",
          "v168","v169","v170","v171","v172","v173","v174","v175",
          "v176","v177","v178","v179","v180","v181","v182","v183",
          "v184","v185","v186","v187","v188","v189","v190","v191");

    __syncthreads();                          // hist read cross-wave below

    // Epilogue: out[b][t] = hist[t] . out_w + out_b, 16 threads per t.
    int tt = tid >> 4, j = tid & 15;
    const float4* hh = (const float4*)(&hist[tt][j * 8]);
    float4 a0q = hh[0], a1q = hh[1];
    const float* owp = out_w + j * 8;
    float pwv = a0q.x * owp[0] + a0q.y * owp[1] + a0q.z * owp[2] + a0q.w * owp[3]
              + a1q.x * owp[4] + a1q.y * owp[5] + a1q.z * owp[6] + a1q.w * owp[7];
#pragma unroll
    for (int off = 8; off > 0; off >>= 1) pwv += __shfl_down(pwv, off, 16);
    if (j == 0) out[b * Tt + tt] = pwv + out_b[0];
}

// ---------------------------------------------------------------------------
extern "C" void kernel_launch(void* const* d_in, const int* in_sizes, int n_in,
                              void* d_out, int out_size, void* d_ws, size_t ws_size,
                              hipStream_t stream) {
    const float* x   = (const float*)d_in[0];
    const float* w1  = (const float*)d_in[1];
    const float* b1  = (const float*)d_in[2];
    const float* w2  = (const float*)d_in[3];
    const float* b2  = (const float*)d_in[4];
    const float* Wf  = (const float*)d_in[5];
    const float* bf  = (const float*)d_in[6];
    const float* Wi  = (const float*)d_in[7];
    const float* bi  = (const float*)d_in[8];
    const float* Wc  = (const float*)d_in[9];
    const float* bc  = (const float*)d_in[10];
    const float* Wo  = (const float*)d_in[11];
    const float* bo  = (const float*)d_in[12];
    const float* ow  = (const float*)d_in[13];
    const float* ob  = (const float*)d_in[14];
    float* out = (float*)d_out;

    float* G = (float*)d_ws;                  // 256*512 = 131072 floats

    convfeat_kernel<<<Bb * Tt, 256, 0, stream>>>(x, w1, b1, w2, b2,
                                                 Wf, bf, Wi, bi, Wc, bc, Wo, bo, G);
    lstm_kernel<<<Bb, 512, 0, stream>>>(G, Wf, Wi, Wc, Wo, ow, ob, out);
}